// Round 12
// baseline (761.464 us; speedup 1.0000x reference)
//
#include <hip/hip_runtime.h>
#include <hip/hip_bf16.h>

#define T_STEPS 32
#define BATCH 256
#define EDIM 512
#define HDIM 512
#define G4 2048       // 4*H
#define VOCAB 3000
#define VPAD 3072
#define NOUT_BLK 48   // 2 row-tiles x 24 col-panels

typedef short bf16x8 __attribute__((ext_vector_type(8)));
typedef float f32x4 __attribute__((ext_vector_type(4)));

__device__ __forceinline__ unsigned short f2b(float f){
  union { float f; unsigned int u; } x; x.f = f;
  unsigned int u = x.u;
  unsigned int r = (u + 0x7fffu + ((u >> 16) & 1u)) >> 16;
  return (unsigned short)r;
}
__device__ __forceinline__ float b2f(unsigned short h){
  union { unsigned int u; float f; } x; x.u = ((unsigned int)h) << 16;
  return x.f;
}
__device__ __forceinline__ float sigm(float x){ return 1.0f / (1.0f + expf(-x)); }

__device__ __forceinline__ void gload_lds16(const unsigned short* g, unsigned short* l){
  __builtin_amdgcn_global_load_lds(
      (const __attribute__((address_space(1))) unsigned int*)g,
      (__attribute__((address_space(3))) unsigned int*)l, 16, 0, 0);
}

#define SB0 __builtin_amdgcn_sched_barrier(0)

// ---------------- small prep kernels ----------------

__global__ void k_cvt_w(const float* __restrict__ wih, const float* __restrict__ whh,
                        unsigned short* __restrict__ o_ih, unsigned short* __restrict__ o_hh){
  int i = blockIdx.x * blockDim.x + threadIdx.x;   // over 2 * G4*512
  int n1 = G4 * EDIM;
  if (i < n1) o_ih[i] = f2b(wih[i]);
  else { int j = i - n1; if (j < G4 * HDIM) o_hh[j] = f2b(whh[j]); }
}

__global__ void k_cvt_wout(const float* __restrict__ in, unsigned short* __restrict__ out){
  int i = blockIdx.x * blockDim.x + threadIdx.x; // over VPAD*1024
  if (i >= VPAD * 1024) return;
  int r = i >> 10, c = i & 1023;
  float v = (r < VOCAB) ? in[r * 1024 + c] : 0.0f;
  out[i] = f2b(v);
}

__global__ void k_build_xs(const float* __restrict__ img, const float* __restrict__ txt,
                           const float* __restrict__ emb, const int* __restrict__ ans,
                           unsigned short* __restrict__ xs){
  int i = blockIdx.x * blockDim.x + threadIdx.x; // over T*B*E
  if (i >= T_STEPS * BATCH * EDIM) return;
  int e = i & (EDIM - 1);
  int r = i >> 9;              // t*B + b
  int t = r >> 8, b = r & 255;
  float v;
  if (t == 0) v = (e < 256) ? img[b * 256 + e] : txt[b * 256 + (e - 256)];
  else { int tok = ans[b * T_STEPS + (t - 1)]; v = emb[(size_t)tok * EDIM + e]; }
  xs[i] = f2b(v);
}

__global__ void k_init_carry(const float* __restrict__ h0, const float* __restrict__ c0,
                             unsigned short* __restrict__ hx, float* __restrict__ cx){
  int i = blockIdx.x * blockDim.x + threadIdx.x;
  if (i < BATCH * HDIM){ hx[i] = f2b(h0[i]); cx[i] = c0[i]; }
}

// batch_sizes, packed row offsets, total rows
__global__ void k_lens(const int* __restrict__ lengths, int* __restrict__ bs,
                       int* __restrict__ roff, int* __restrict__ meta){
  __shared__ int s[T_STEPS];
  int t = threadIdx.x; // 64 threads
  if (t < T_STEPS){
    int c = 0;
    for (int i = 0; i < BATCH; i++) c += (lengths[i] > t) ? 1 : 0;
    s[t] = c; bs[t] = c;
  }
  __syncthreads();
  if (t == 0){
    int acc = 0;
    for (int u = 0; u < T_STEPS; u++){ roff[u] = acc; acc += s[u]; }
    meta[0] = acc;
  }
}

// ---------------- staged 128x128 GEMM core, BK=64, XOR-swizzled LDS ----------------
template<int K>
__device__ __forceinline__ void gemm_tile(const unsigned short* __restrict__ A,
                                          const unsigned short* __restrict__ B,
                                          int row0, int col0,
                                          unsigned short* As, unsigned short* Bs,
                                          f32x4 acc[4][4]){
  const int tid = threadIdx.x, w = tid >> 6, l = tid & 63;
  const int la = l & 15, lkq = l >> 4;
  const int sr = l >> 3;            // row within 8-row staging group
  const int ss = (l & 7) ^ sr;      // pre-swizzled source slot
  const int wr = (w >> 1) * 64, wc = (w & 1) * 64;
  const unsigned short* gA = A + (size_t)(row0 + w * 32 + sr) * K + ss * 8;
  const unsigned short* gB = B + (size_t)(col0 + w * 32 + sr) * K + ss * 8;
  unsigned short* lA = As + (w * 32) * 64;
  unsigned short* lB = Bs + (w * 32) * 64;
  for (int k0 = 0; k0 < K; k0 += 64){
#pragma unroll
    for (int i = 0; i < 4; i++){
      gload_lds16(gA + (size_t)i * 8 * K + k0, lA + i * 8 * 64);
      gload_lds16(gB + (size_t)i * 8 * K + k0, lB + i * 8 * 64);
    }
    __syncthreads();
#pragma unroll
    for (int kk = 0; kk < 2; kk++){
      bf16x8 a[4], b[4];
#pragma unroll
      for (int i = 0; i < 4; i++){
        int r = wr + i * 16 + la;
        a[i] = *(const bf16x8*)(As + r * 64 + (((kk * 4 + lkq) ^ (r & 7)) << 3));
      }
#pragma unroll
      for (int i = 0; i < 4; i++){
        int r = wc + i * 16 + la;
        b[i] = *(const bf16x8*)(Bs + r * 64 + (((kk * 4 + lkq) ^ (r & 7)) << 3));
      }
#pragma unroll
      for (int mi = 0; mi < 4; mi++)
#pragma unroll
        for (int ni = 0; ni < 4; ni++)
          acc[mi][ni] = __builtin_amdgcn_mfma_f32_16x16x32_bf16(a[mi], b[ni], acc[mi][ni], 0, 0, 0);
    }
    __syncthreads();
  }
}

// ---------------- GEMM 1: XW = xs @ W_ih^T + b_ih + b_hh (bf16 out) ----------------
__global__ __launch_bounds__(256) void k_gemm_xw(const unsigned short* __restrict__ A,
                                                 const unsigned short* __restrict__ W,
                                                 const float* __restrict__ bih,
                                                 const float* __restrict__ bhh,
                                                 unsigned short* __restrict__ C){
  __shared__ unsigned short As[128 * 64], Bs[128 * 64];
  int bid = blockIdx.x;
  int xcd = bid & 7, idx = bid >> 3;          // idx 0..127
  int by = xcd * 2 + (idx & 1);               // 16 col-panels, 2 per XCD
  int bx = idx >> 1;                          // 64 row-blocks
  int row0 = bx * 128, col0 = by * 128;
  f32x4 acc[4][4] = {};
  gemm_tile<EDIM>(A, W, row0, col0, As, Bs, acc);
  int tid = threadIdx.x, w = tid >> 6, l = tid & 63;
  int la = l & 15, r4 = (l >> 4) * 4;
  int wr = (w >> 1) * 64, wc = (w & 1) * 64;
#pragma unroll
  for (int ni = 0; ni < 4; ni++){
    int col = col0 + wc + ni * 16 + la;
    float bias = bih[col] + bhh[col];
#pragma unroll
    for (int mi = 0; mi < 4; mi++)
#pragma unroll
      for (int j = 0; j < 4; j++){
        int row = row0 + wr + mi * 16 + r4 + j;
        C[(size_t)row * G4 + col] = f2b(acc[mi][ni][j] + bias);
      }
  }
}

// ---------------- fused step: out-blocks (timestep t-1 projection) + chain blocks ----
// grid = 48 out-blocks (dispatched FIRST) + 512 chain blocks. 64 KB LDS union.
__global__ __launch_bounds__(256, 2) void k_step_fused(
    int t,
    const unsigned short* __restrict__ XW,
    const unsigned short* __restrict__ Whh,
    unsigned short* __restrict__ hbA,
    unsigned short* __restrict__ hbB,
    float* __restrict__ cxio,
    unsigned short* __restrict__ hs,
    unsigned short* __restrict__ cs,
    const int* __restrict__ bs,
    const int* __restrict__ roff,
    const unsigned short* __restrict__ Wo,
    const float* __restrict__ bout,
    float* __restrict__ out){
  __shared__ unsigned char smem[65536];
  const int bid = blockIdx.x;
  const int tid = threadIdx.x, w = tid >> 6, l = tid & 63;
  const int la = l & 15, lkq = l >> 4;

  if (bid < NOUT_BLK){
    // ================= OUTPUT ROLE: project timestep tt = t-1 =================
    const int tt = t - 1;
    if (tt < 0) return;
    const int rows_t = bs[tt];
    const int ort = bid & 1, ocp = bid >> 1;
    const int lrow0 = ort * 128;
    if (lrow0 >= rows_t) return;
    const int col0 = ocp * 128;
    const int orow0 = roff[tt] + lrow0;
    const unsigned short* Ah = hs + ((size_t)tt * BATCH + lrow0) * 512;
    const unsigned short* Ac = cs + ((size_t)tt * BATCH + lrow0) * 512;
    unsigned short* lAs = (unsigned short*)smem;            // [2][8192]
    unsigned short* lBs = (unsigned short*)(smem + 32768);  // [2][8192]
    const int sr = l >> 3, ss = (l & 7) ^ sr;
    const int wr = (w >> 1) * 64, wc = (w & 1) * 64;
    const unsigned short* gB = Wo + (size_t)(col0 + w * 32 + sr) * 1024 + ss * 8;
    f32x4 acc[4][4] = {};

#define STG_O(BUF, K0)                                                            \
  { _Pragma("unroll")                                                             \
    for (int i = 0; i < 4; i++){                                                  \
      const unsigned short* srcA = ((K0) < 512)                                   \
          ? Ah + (size_t)(w * 32 + sr + i * 8) * 512 + (K0) + ss * 8              \
          : Ac + (size_t)(w * 32 + sr + i * 8) * 512 + ((K0) - 512) + ss * 8;     \
      gload_lds16(srcA, lAs + (BUF) * 8192 + (w * 32 + i * 8) * 64);              \
      gload_lds16(gB + (size_t)i * 8 * 1024 + (K0), lBs + (BUF) * 8192 + (w * 32 + i * 8) * 64); \
    } }

    STG_O(0, 0);
    asm volatile("s_waitcnt vmcnt(0)" ::: "memory"); SB0;
    __builtin_amdgcn_s_barrier(); SB0;
    for (int kt = 0; kt < 16; ++kt){
      int cur = kt & 1;
      if (kt + 1 < 16){
        STG_O(cur ^ 1, (kt + 1) * 64); SB0;
        asm volatile("s_waitcnt vmcnt(8)" ::: "memory");
      } else {
        asm volatile("s_waitcnt vmcnt(0)" ::: "memory");
      }
      SB0; __builtin_amdgcn_s_barrier(); SB0;
      const unsigned short* As = lAs + cur * 8192;
      const unsigned short* Bs = lBs + cur * 8192;
#pragma unroll
      for (int kk = 0; kk < 2; kk++){
        bf16x8 a[4], b[4];
#pragma unroll
        for (int i = 0; i < 4; i++){
          int r = wr + i * 16 + la;
          a[i] = *(const bf16x8*)(As + r * 64 + (((kk * 4 + lkq) ^ (r & 7)) << 3));
        }
#pragma unroll
        for (int i = 0; i < 4; i++){
          int r = wc + i * 16 + la;
          b[i] = *(const bf16x8*)(Bs + r * 64 + (((kk * 4 + lkq) ^ (r & 7)) << 3));
        }
#pragma unroll
        for (int mi = 0; mi < 4; mi++)
#pragma unroll
          for (int ni = 0; ni < 4; ni++)
            acc[mi][ni] = __builtin_amdgcn_mfma_f32_16x16x32_bf16(a[mi], b[ni], acc[mi][ni], 0, 0, 0);
      }
      SB0; __builtin_amdgcn_s_barrier(); SB0;
    }
#undef STG_O
    const int nvalid = rows_t - lrow0;    // rows valid in this tile
    int r4 = lkq * 4;
#pragma unroll
    for (int ni = 0; ni < 4; ni++){
      int col = col0 + wc + ni * 16 + la;
      if (col >= VOCAB) continue;
      float bias = bout[col];
#pragma unroll
      for (int mi = 0; mi < 4; mi++)
#pragma unroll
        for (int j = 0; j < 4; j++){
          int lr = wr + mi * 16 + r4 + j;
          if (lr < nvalid) out[(size_t)(orow0 + lr) * VOCAB + col] = acc[mi][ni][j] + bias;
        }
    }
    return;
  }

  // ================= CHAIN ROLE: LSTM step t =================
  if (t >= T_STEPS) return;
  const int cbid = bid - NOUT_BLK;
  const int row0 = (cbid & 15) * 16;
  const int hc0  = (cbid >> 4) * 16;
  const unsigned short* XWt = XW + (size_t)t * BATCH * G4;
  const unsigned short* hin = (t & 1) ? hbB : hbA;
  unsigned short* hout = (t & 1) ? hbA : hbB;
  unsigned short* hs_t = hs + (size_t)t * BATCH * HDIM;
  unsigned short* cs_t = cs + (size_t)t * BATCH * HDIM;
  const int do_res = (t >= 2 && (t % 3) == 0);
  const int tm2 = (t >= 2) ? (t - 2) : 0;
  const unsigned short* hs_m2 = hs + (size_t)tm2 * BATCH * HDIM;
  const unsigned short* cs_m2 = cs + (size_t)tm2 * BATCH * HDIM;

  unsigned short* hA = (unsigned short*)smem;                 // 16 x 512 swizzled
  float (*gbuf)[16][17] = (float(*)[16][17])(smem + 16384);   // [4][16][17]

#pragma unroll
  for (int i = 0; i < 4; i++){
    int r = i * 4 + w;
    gload_lds16(hin + (size_t)(row0 + r) * HDIM + ((l ^ (r & 7)) << 3), hA + r * 512);
  }
  const unsigned short* Bp = Whh + (size_t)(w * HDIM + hc0 + la) * HDIM + lkq * 8;
  bf16x8 b[16];
#pragma unroll
  for (int kk = 0; kk < 16; kk++) b[kk] = *(const bf16x8*)(Bp + kk * 32);
  const int r4 = lkq * 4;
  float x[4];
#pragma unroll
  for (int j = 0; j < 4; j++)
    x[j] = b2f(XWt[(size_t)(row0 + r4 + j) * G4 + w * HDIM + hc0 + la]);
  __syncthreads();
  f32x4 acc = {};
#pragma unroll
  for (int kk = 0; kk < 16; kk++){
    bf16x8 a = *(const bf16x8*)(hA + la * 512 + (((kk * 4 + lkq) ^ (la & 7)) << 3));
    acc = __builtin_amdgcn_mfma_f32_16x16x32_bf16(a, b[kk], acc, 0, 0, 0);
  }
#pragma unroll
  for (int j = 0; j < 4; j++) gbuf[w][r4 + j][la] = acc[j] + x[j];
  __syncthreads();
  {
    int r = tid >> 4, c = tid & 15;
    size_t p = (size_t)(row0 + r) * HDIM + hc0 + c;
    float gi = gbuf[0][r][c], gf = gbuf[1][r][c], gg = gbuf[2][r][c], go = gbuf[3][r][c];
    float cprev = cxio[p];
    float cy = sigm(gf) * cprev + sigm(gi) * tanhf(gg);
    float hy = sigm(go) * tanhf(cy);
    hs_t[p] = f2b(hy);
    cs_t[p] = f2b(cy);
    float hn = hy, cn = cy;
    if (do_res){ hn += b2f(hs_m2[p]); cn += b2f(cs_m2[p]); }
    hout[p] = f2b(hn);
    cxio[p] = cn;
  }
}

extern "C" void kernel_launch(void* const* d_in, const int* in_sizes, int n_in,
                              void* d_out, int out_size, void* d_ws, size_t ws_size,
                              hipStream_t stream){
  const float* img   = (const float*)d_in[0];
  const float* txt   = (const float*)d_in[1];
  const float* h0    = (const float*)d_in[2];
  const float* c0    = (const float*)d_in[3];
  const float* emb   = (const float*)d_in[4];
  const float* W_ih  = (const float*)d_in[5];
  const float* W_hh  = (const float*)d_in[6];
  const float* b_ih  = (const float*)d_in[7];
  const float* b_hh  = (const float*)d_in[8];
  const float* W_out = (const float*)d_in[9];
  const float* b_out = (const float*)d_in[10];
  const int* answer  = (const int*)d_in[11];
  const int* lengths = (const int*)d_in[12];
  float* out = (float*)d_out;

  char* ws = (char*)d_ws;
  size_t off = 0;
  auto alloc = [&](size_t bytes) -> void* {
    void* p = ws + off; off += (bytes + 255) & ~(size_t)255; return p;
  };
  unsigned short* Wih_b = (unsigned short*)alloc((size_t)G4 * EDIM * 2);
  unsigned short* Whh_b = (unsigned short*)alloc((size_t)G4 * HDIM * 2);
  unsigned short* Wo_b  = (unsigned short*)alloc((size_t)VPAD * 1024 * 2);
  unsigned short* xs    = (unsigned short*)alloc((size_t)T_STEPS * BATCH * EDIM * 2);
  unsigned short* XW    = (unsigned short*)alloc((size_t)T_STEPS * BATCH * G4 * 2);
  unsigned short* hs    = (unsigned short*)alloc((size_t)T_STEPS * BATCH * HDIM * 2);
  unsigned short* cs    = (unsigned short*)alloc((size_t)T_STEPS * BATCH * HDIM * 2);
  unsigned short* hxA   = (unsigned short*)alloc((size_t)BATCH * HDIM * 2);
  unsigned short* hxB   = (unsigned short*)alloc((size_t)BATCH * HDIM * 2);
  float* cx             = (float*)alloc((size_t)BATCH * HDIM * 4);
  int* bsz  = (int*)alloc(T_STEPS * 4);
  int* roff = (int*)alloc(T_STEPS * 4);
  int* meta = (int*)alloc(256);

  k_cvt_w<<<(2 * G4 * EDIM + 255) / 256, 256, 0, stream>>>(W_ih, W_hh, Wih_b, Whh_b);
  k_cvt_wout<<<(VPAD * 1024 + 255) / 256, 256, 0, stream>>>(W_out, Wo_b);
  k_build_xs<<<(T_STEPS * BATCH * EDIM + 255) / 256, 256, 0, stream>>>(img, txt, emb, answer, xs);
  k_init_carry<<<(BATCH * HDIM + 255) / 256, 256, 0, stream>>>(h0, c0, hxA, cx);
  k_lens<<<1, 64, 0, stream>>>(lengths, bsz, roff, meta);

  k_gemm_xw<<<dim3(1024), 256, 0, stream>>>(xs, Wih_b, b_ih, b_hh, XW);

  for (int t = 0; t <= T_STEPS; t++){
    k_step_fused<<<dim3(NOUT_BLK + 512), 256, 0, stream>>>(
        t, XW, Whh_b, hxA, hxB, cx, hs, cs, bsz, roff, Wo_b, b_out, out);
  }
}

// Round 13
// 493.920 us; speedup vs baseline: 1.5417x; 1.5417x over previous
//
#include <hip/hip_runtime.h>
#include <hip/hip_bf16.h>

#define T_STEPS 32
#define BATCH 256
#define EDIM 512
#define HDIM 512
#define G4 2048       // 4*H
#define VOCAB 3000
#define VPAD 3072

typedef short bf16x8 __attribute__((ext_vector_type(8)));
typedef float f32x4 __attribute__((ext_vector_type(4)));

__device__ __forceinline__ unsigned short f2b(float f){
  union { float f; unsigned int u; } x; x.f = f;
  unsigned int u = x.u;
  unsigned int r = (u + 0x7fffu + ((u >> 16) & 1u)) >> 16;
  return (unsigned short)r;
}
__device__ __forceinline__ float b2f(unsigned short h){
  union { unsigned int u; float f; } x; x.u = ((unsigned int)h) << 16;
  return x.f;
}
__device__ __forceinline__ float sigm(float x){ return 1.0f / (1.0f + expf(-x)); }

__device__ __forceinline__ void gload_lds16(const unsigned short* g, unsigned short* l){
  __builtin_amdgcn_global_load_lds(
      (const __attribute__((address_space(1))) unsigned int*)g,
      (__attribute__((address_space(3))) unsigned int*)l, 16, 0, 0);
}

#define SB0 __builtin_amdgcn_sched_barrier(0)

// ---------------- small prep kernels ----------------

__global__ void k_cvt_w(const float* __restrict__ wih, const float* __restrict__ whh,
                        unsigned short* __restrict__ o_ih, unsigned short* __restrict__ o_hh){
  int i = blockIdx.x * blockDim.x + threadIdx.x;   // over 2 * G4*512
  int n1 = G4 * EDIM;
  if (i < n1) o_ih[i] = f2b(wih[i]);
  else { int j = i - n1; if (j < G4 * HDIM) o_hh[j] = f2b(whh[j]); }
}

__global__ void k_cvt_wout(const float* __restrict__ in, unsigned short* __restrict__ out){
  int i = blockIdx.x * blockDim.x + threadIdx.x; // over VPAD*1024
  if (i >= VPAD * 1024) return;
  int r = i >> 10, c = i & 1023;
  float v = (r < VOCAB) ? in[r * 1024 + c] : 0.0f;
  out[i] = f2b(v);
}

__global__ void k_build_xs(const float* __restrict__ img, const float* __restrict__ txt,
                           const float* __restrict__ emb, const int* __restrict__ ans,
                           unsigned short* __restrict__ xs){
  int i = blockIdx.x * blockDim.x + threadIdx.x; // over T*B*E
  if (i >= T_STEPS * BATCH * EDIM) return;
  int e = i & (EDIM - 1);
  int r = i >> 9;              // t*B + b
  int t = r >> 8, b = r & 255;
  float v;
  if (t == 0) v = (e < 256) ? img[b * 256 + e] : txt[b * 256 + (e - 256)];
  else { int tok = ans[b * T_STEPS + (t - 1)]; v = emb[(size_t)tok * EDIM + e]; }
  xs[i] = f2b(v);
}

__global__ void k_init_carry(const float* __restrict__ h0, const float* __restrict__ c0,
                             unsigned short* __restrict__ hx, float* __restrict__ cx){
  int i = blockIdx.x * blockDim.x + threadIdx.x;
  if (i < BATCH * HDIM){ hx[i] = f2b(h0[i]); cx[i] = c0[i]; }
}

// batch_sizes, packed row offsets, total rows, dest->src row map
__global__ void k_lens(const int* __restrict__ lengths, int* __restrict__ bs,
                       int* __restrict__ roff, int* __restrict__ meta,
                       int* __restrict__ rmap){
  __shared__ int s[T_STEPS];
  __shared__ int sroff[T_STEPS + 1];
  int t = threadIdx.x; // 64 threads
  if (t < T_STEPS){
    int c = 0;
    for (int i = 0; i < BATCH; i++) c += (lengths[i] > t) ? 1 : 0;
    s[t] = c; bs[t] = c;
  }
  __syncthreads();
  if (t == 0){
    int acc = 0;
    for (int u = 0; u < T_STEPS; u++){ sroff[u] = acc; roff[u] = acc; acc += s[u]; }
    sroff[T_STEPS] = acc;
    meta[0] = acc;
  }
  __syncthreads();
  int ntot = sroff[T_STEPS];
  for (int r = t; r < T_STEPS * BATCH; r += 64){
    int tt = r >> 8, b = r & 255;
    if (b < s[tt]) rmap[sroff[tt] + b] = r;
  }
  for (int r = ntot + t; r < T_STEPS * BATCH; r += 64) rmap[r] = -1;
}

// ---------------- staged 128x128 GEMM core, BK=64, XOR-swizzled LDS ----------------
template<int K>
__device__ __forceinline__ void gemm_tile(const unsigned short* __restrict__ A,
                                          const unsigned short* __restrict__ B,
                                          int row0, int col0,
                                          unsigned short* As, unsigned short* Bs,
                                          f32x4 acc[4][4]){
  const int tid = threadIdx.x, w = tid >> 6, l = tid & 63;
  const int la = l & 15, lkq = l >> 4;
  const int sr = l >> 3;            // row within 8-row staging group
  const int ss = (l & 7) ^ sr;      // pre-swizzled source slot
  const int wr = (w >> 1) * 64, wc = (w & 1) * 64;
  const unsigned short* gA = A + (size_t)(row0 + w * 32 + sr) * K + ss * 8;
  const unsigned short* gB = B + (size_t)(col0 + w * 32 + sr) * K + ss * 8;
  unsigned short* lA = As + (w * 32) * 64;
  unsigned short* lB = Bs + (w * 32) * 64;
  for (int k0 = 0; k0 < K; k0 += 64){
#pragma unroll
    for (int i = 0; i < 4; i++){
      gload_lds16(gA + (size_t)i * 8 * K + k0, lA + i * 8 * 64);
      gload_lds16(gB + (size_t)i * 8 * K + k0, lB + i * 8 * 64);
    }
    __syncthreads();
#pragma unroll
    for (int kk = 0; kk < 2; kk++){
      bf16x8 a[4], b[4];
#pragma unroll
      for (int i = 0; i < 4; i++){
        int r = wr + i * 16 + la;
        a[i] = *(const bf16x8*)(As + r * 64 + (((kk * 4 + lkq) ^ (r & 7)) << 3));
      }
#pragma unroll
      for (int i = 0; i < 4; i++){
        int r = wc + i * 16 + la;
        b[i] = *(const bf16x8*)(Bs + r * 64 + (((kk * 4 + lkq) ^ (r & 7)) << 3));
      }
#pragma unroll
      for (int mi = 0; mi < 4; mi++)
#pragma unroll
        for (int ni = 0; ni < 4; ni++)
          acc[mi][ni] = __builtin_amdgcn_mfma_f32_16x16x32_bf16(a[mi], b[ni], acc[mi][ni], 0, 0, 0);
    }
    __syncthreads();
  }
}

// ---------------- GEMM 1: XW = xs @ W_ih^T + b_ih + b_hh (bf16 out) ----------------
__global__ __launch_bounds__(256) void k_gemm_xw(const unsigned short* __restrict__ A,
                                                 const unsigned short* __restrict__ W,
                                                 const float* __restrict__ bih,
                                                 const float* __restrict__ bhh,
                                                 unsigned short* __restrict__ C){
  __shared__ unsigned short As[128 * 64], Bs[128 * 64];
  int bid = blockIdx.x;
  int xcd = bid & 7, idx = bid >> 3;          // idx 0..127
  int by = xcd * 2 + (idx & 1);               // 16 col-panels, 2 per XCD
  int bx = idx >> 1;                          // 64 row-blocks
  int row0 = bx * 128, col0 = by * 128;
  f32x4 acc[4][4] = {};
  gemm_tile<EDIM>(A, W, row0, col0, As, Bs, acc);
  int tid = threadIdx.x, w = tid >> 6, l = tid & 63;
  int la = l & 15, r4 = (l >> 4) * 4;
  int wr = (w >> 1) * 64, wc = (w & 1) * 64;
#pragma unroll
  for (int ni = 0; ni < 4; ni++){
    int col = col0 + wc + ni * 16 + la;
    float bias = bih[col] + bhh[col];
#pragma unroll
    for (int mi = 0; mi < 4; mi++)
#pragma unroll
      for (int j = 0; j < 4; j++){
        int row = row0 + wr + mi * 16 + r4 + j;
        C[(size_t)row * G4 + col] = f2b(acc[mi][ni][j] + bias);
      }
  }
}

// ---------------- fused recurrent step: 1024 blocks (8 rows x 16 hcols), wave=gate ----
// 4 blocks/CU -> 4 waves/SIMD (vs 2 at 512 blocks). MFMA rows 8-15 duplicate rows 0-7
// (A-frag reads row la&7) and are masked at the gbuf write. Numerics identical.
__global__ __launch_bounds__(256, 4) void k_lstm_step(
    const unsigned short* __restrict__ XWt,
    const unsigned short* __restrict__ Whh,
    const unsigned short* __restrict__ hin,
    unsigned short* __restrict__ hout,
    float* __restrict__ cxio,
    unsigned short* __restrict__ hs_t,
    unsigned short* __restrict__ cs_t,
    const unsigned short* __restrict__ hs_m2,
    const unsigned short* __restrict__ cs_m2,
    int do_res){
  __shared__ unsigned short hA[8 * 512];    // swizzled h tile (8 rows)
  __shared__ float gbuf[4][8][17];
  const int w = threadIdx.x >> 6, l = threadIdx.x & 63;
  const int la = l & 15, lkq = l >> 4;
  const int row0 = blockIdx.x * 8;
  const int hc0  = blockIdx.y * 16;
  // stage 8 rows: wave w stages rows {w, 4+w}; source slot pre-swizzled, LDS dest linear
#pragma unroll
  for (int i = 0; i < 2; i++){
    int r = i * 4 + w;
    gload_lds16(hin + (size_t)(row0 + r) * HDIM + ((l ^ r) << 3), hA + r * 512);
  }
  // hoist ALL 16 Whh B-fragments (independent, issued back-to-back)
  const unsigned short* Bp = Whh + (size_t)(w * HDIM + hc0 + la) * HDIM + lkq * 8;
  bf16x8 b[16];
#pragma unroll
  for (int kk = 0; kk < 16; kk++) b[kk] = *(const bf16x8*)(Bp + kk * 32);
  // hoist XW (rows 0..7 only; guard keeps row0=248 block in bounds)
  const int r4 = lkq * 4;
  float x[4];
#pragma unroll
  for (int j = 0; j < 4; j++)
    x[j] = (lkq < 2) ? b2f(XWt[(size_t)(row0 + r4 + j) * G4 + w * HDIM + hc0 + la]) : 0.0f;
  __syncthreads();
  f32x4 acc = {};
#pragma unroll
  for (int kk = 0; kk < 16; kk++){
    bf16x8 a = *(const bf16x8*)(hA + (la & 7) * 512 + (((kk * 4 + lkq) ^ (la & 7)) << 3));
    acc = __builtin_amdgcn_mfma_f32_16x16x32_bf16(a, b[kk], acc, 0, 0, 0);
  }
  if (lkq < 2){
#pragma unroll
    for (int j = 0; j < 4; j++) gbuf[w][r4 + j][la] = acc[j] + x[j];
  }
  __syncthreads();
  if (threadIdx.x < 128){
    int r = threadIdx.x >> 4, c = threadIdx.x & 15;
    size_t p = (size_t)(row0 + r) * HDIM + hc0 + c;
    float gi = gbuf[0][r][c], gf = gbuf[1][r][c], gg = gbuf[2][r][c], go = gbuf[3][r][c];
    float cprev = cxio[p];
    float cy = sigm(gf) * cprev + sigm(gi) * tanhf(gg);
    float hy = sigm(go) * tanhf(cy);
    hs_t[p] = f2b(hy);
    cs_t[p] = f2b(cy);
    float hn = hy, cn = cy;
    if (do_res){ hn += b2f(hs_m2[p]); cn += b2f(cs_m2[p]); }
    hout[p] = f2b(hn);
    cxio[p] = cn;
  }
}

// ---------------- GEMM 2: 8-phase pipelined 256x128, 3-slot LDS, counted vmcnt ----------------
__global__ __launch_bounds__(512) void k_gemm_out(const unsigned short* __restrict__ hs,
                                                  const unsigned short* __restrict__ cs,
                                                  const unsigned short* __restrict__ Wo,
                                                  const float* __restrict__ bout,
                                                  const int* __restrict__ meta,
                                                  const int* __restrict__ rmap,
                                                  float* __restrict__ out){
  const int ntot = meta[0];
  const int row0 = blockIdx.x * 256, col0 = blockIdx.y * 128;
  if (row0 >= ntot) return;
  __shared__ unsigned short As[3][256 * 64];   // 96 KB
  __shared__ unsigned short Bs[3][128 * 64];   // 48 KB
  const int t = threadIdx.x, w = t >> 6, l = t & 63;
  const int la = l & 15, lkq = l >> 4;
  const int wm = w >> 2, wn = w & 3;
  const int tr = t >> 3, ss = (t & 7) ^ (tr & 7);
  int srowA[4];
#pragma unroll
  for (int p = 0; p < 4; p++){
    int rr = rmap[row0 + p * 64 + tr];
    srowA[p] = rr < 0 ? 0 : rr;
  }
  f32x4 acc[8][2] = {};

#define STG_A(KT2, P) gload_lds16(                                              \
    ((KT2) < 8 ? hs : cs) + (size_t)srowA[P] * 512 + ((KT2) & 7) * 64 + ss * 8, \
    &As[(KT2) % 3][((P) * 64 + w * 8) * 64])
#define STG_B(KT2, Q) gload_lds16(                                              \
    Wo + (size_t)(col0 + (Q) * 64 + tr) * 1024 + (KT2) * 64 + ss * 8,           \
    &Bs[(KT2) % 3][((Q) * 64 + w * 8) * 64])

  STG_A(0,0); STG_A(0,1); STG_A(0,2); STG_A(0,3); STG_B(0,0); STG_B(0,1);
  STG_A(1,0); STG_A(1,1); STG_A(1,2); STG_A(1,3); STG_B(1,0); STG_B(1,1);
  SB0;
  asm volatile("s_waitcnt vmcnt(6)" ::: "memory");
  SB0; __builtin_amdgcn_s_barrier(); SB0;

  for (int kt = 0; kt < 16; ++kt){
    const unsigned short* Acur = As[kt % 3];
    const unsigned short* Bcur = Bs[kt % 3];
    const int kt2 = kt + 2;
    const bool st = (kt2 < 16);
    bf16x8 b[2][2];
    {
#pragma unroll
      for (int nf = 0; nf < 2; nf++){
        int rc = wn * 32 + nf * 16 + la;
#pragma unroll
        for (int kk = 0; kk < 2; kk++)
          b[nf][kk] = *(const bf16x8*)(Bcur + rc * 64 + (((kk * 4 + lkq) ^ (rc & 7)) << 3));
      }
      bf16x8 a[4][2];
#pragma unroll
      for (int m2 = 0; m2 < 4; m2++){
        int rr = wm * 128 + m2 * 16 + la;
#pragma unroll
        for (int kk = 0; kk < 2; kk++)
          a[m2][kk] = *(const bf16x8*)(Acur + rr * 64 + (((kk * 4 + lkq) ^ (rr & 7)) << 3));
      }
      if (st){ STG_A(kt2,0); STG_A(kt2,1); STG_B(kt2,0); }
      SB0; __builtin_amdgcn_s_barrier();
      asm volatile("s_waitcnt lgkmcnt(0)" ::: "memory");
      SB0;
      __builtin_amdgcn_s_setprio(1);
#pragma unroll
      for (int m2 = 0; m2 < 4; m2++)
#pragma unroll
        for (int nf = 0; nf < 2; nf++)
#pragma unroll
          for (int kk = 0; kk < 2; kk++)
            acc[m2][nf] = __builtin_amdgcn_mfma_f32_16x16x32_bf16(a[m2][kk], b[nf][kk], acc[m2][nf], 0, 0, 0);
      __builtin_amdgcn_s_setprio(0);
      SB0; __builtin_amdgcn_s_barrier(); SB0;
    }
    {
      bf16x8 a[4][2];
#pragma unroll
      for (int m2 = 0; m2 < 4; m2++){
        int rr = wm * 128 + (4 + m2) * 16 + la;
#pragma unroll
        for (int kk = 0; kk < 2; kk++)
          a[m2][kk] = *(const bf16x8*)(Acur + rr * 64 + (((kk * 4 + lkq) ^ (rr & 7)) << 3));
      }
      if (st){ STG_A(kt2,2); STG_A(kt2,3); STG_B(kt2,1); }
      SB0; __builtin_amdgcn_s_barrier();
      asm volatile("s_waitcnt lgkmcnt(0)" ::: "memory");
      SB0;
      __builtin_amdgcn_s_setprio(1);
#pragma unroll
      for (int m2 = 0; m2 < 4; m2++)
#pragma unroll
        for (int nf = 0; nf < 2; nf++)
#pragma unroll
          for (int kk = 0; kk < 2; kk++)
            acc[4 + m2][nf] = __builtin_amdgcn_mfma_f32_16x16x32_bf16(a[m2][kk], b[nf][kk], acc[4 + m2][nf], 0, 0, 0);
      __builtin_amdgcn_s_setprio(0);
      SB0;
      if (kt <= 13){ asm volatile("s_waitcnt vmcnt(6)" ::: "memory"); }
      else if (kt == 14){ asm volatile("s_waitcnt vmcnt(0)" ::: "memory"); }
      SB0; __builtin_amdgcn_s_barrier(); SB0;
    }
  }
#undef STG_A
#undef STG_B
#pragma unroll
  for (int nf = 0; nf < 2; nf++){
    int col = col0 + wn * 32 + nf * 16 + la;
    if (col >= VOCAB) continue;
    float bias = bout[col];
#pragma unroll
    for (int mf = 0; mf < 8; mf++)
#pragma unroll
      for (int j = 0; j < 4; j++){
        int row = row0 + wm * 128 + mf * 16 + lkq * 4 + j;
        if (row < ntot) out[(size_t)row * VOCAB + col] = acc[mf][nf][j] + bias;
      }
  }
}

extern "C" void kernel_launch(void* const* d_in, const int* in_sizes, int n_in,
                              void* d_out, int out_size, void* d_ws, size_t ws_size,
                              hipStream_t stream){
  const float* img   = (const float*)d_in[0];
  const float* txt   = (const float*)d_in[1];
  const float* h0    = (const float*)d_in[2];
  const float* c0    = (const float*)d_in[3];
  const float* emb   = (const float*)d_in[4];
  const float* W_ih  = (const float*)d_in[5];
  const float* W_hh  = (const float*)d_in[6];
  const float* b_ih  = (const float*)d_in[7];
  const float* b_hh  = (const float*)d_in[8];
  const float* W_out = (const float*)d_in[9];
  const float* b_out = (const float*)d_in[10];
  const int* answer  = (const int*)d_in[11];
  const int* lengths = (const int*)d_in[12];
  float* out = (float*)d_out;

  char* ws = (char*)d_ws;
  size_t off = 0;
  auto alloc = [&](size_t bytes) -> void* {
    void* p = ws + off; off += (bytes + 255) & ~(size_t)255; return p;
  };
  unsigned short* Wih_b = (unsigned short*)alloc((size_t)G4 * EDIM * 2);
  unsigned short* Whh_b = (unsigned short*)alloc((size_t)G4 * HDIM * 2);
  unsigned short* Wo_b  = (unsigned short*)alloc((size_t)VPAD * 1024 * 2);
  unsigned short* xs    = (unsigned short*)alloc((size_t)T_STEPS * BATCH * EDIM * 2);
  unsigned short* XW    = (unsigned short*)alloc((size_t)T_STEPS * BATCH * G4 * 2);
  unsigned short* hs    = (unsigned short*)alloc((size_t)T_STEPS * BATCH * HDIM * 2);
  unsigned short* cs    = (unsigned short*)alloc((size_t)T_STEPS * BATCH * HDIM * 2);
  unsigned short* hxA   = (unsigned short*)alloc((size_t)BATCH * HDIM * 2);
  unsigned short* hxB   = (unsigned short*)alloc((size_t)BATCH * HDIM * 2);
  float* cx             = (float*)alloc((size_t)BATCH * HDIM * 4);
  int* bsz  = (int*)alloc(T_STEPS * 4);
  int* roff = (int*)alloc(T_STEPS * 4);
  int* meta = (int*)alloc(256);
  int* rmap = (int*)alloc(T_STEPS * BATCH * 4);

  k_cvt_w<<<(2 * G4 * EDIM + 255) / 256, 256, 0, stream>>>(W_ih, W_hh, Wih_b, Whh_b);
  k_cvt_wout<<<(VPAD * 1024 + 255) / 256, 256, 0, stream>>>(W_out, Wo_b);
  k_build_xs<<<(T_STEPS * BATCH * EDIM + 255) / 256, 256, 0, stream>>>(img, txt, emb, answer, xs);
  k_init_carry<<<(BATCH * HDIM + 255) / 256, 256, 0, stream>>>(h0, c0, hxA, cx);
  k_lens<<<1, 64, 0, stream>>>(lengths, bsz, roff, meta, rmap);

  k_gemm_xw<<<dim3(1024), 256, 0, stream>>>(xs, Wih_b, b_ih, b_hh, XW);

  unsigned short* hbuf[2] = { hxA, hxB };
  for (int t = 0; t < T_STEPS; t++){
    int do_res = (t >= 2 && (t % 3) == 0) ? 1 : 0;
    int tm2 = (t >= 2) ? (t - 2) : 0;
    k_lstm_step<<<dim3(BATCH / 8, HDIM / 16), 256, 0, stream>>>(
        XW + (size_t)t * BATCH * G4, Whh_b, hbuf[t & 1], hbuf[(t + 1) & 1], cx,
        hs + (size_t)t * BATCH * HDIM, cs + (size_t)t * BATCH * HDIM,
        hs + (size_t)tm2 * BATCH * HDIM, cs + (size_t)tm2 * BATCH * HDIM, do_res);
  }

  k_gemm_out<<<dim3(T_STEPS * BATCH / 256, VPAD / 128), 512, 0, stream>>>(hs, cs, Wo_b, b_out, meta, rmap, out);
}

// Round 14
// 336.528 us; speedup vs baseline: 2.2627x; 1.4677x over previous
//
#include <hip/hip_runtime.h>
#include <hip/hip_bf16.h>

#define T_STEPS 32
#define BATCH 256
#define EDIM 512
#define HDIM 512
#define G4 2048       // 4*H
#define VOCAB 3000
#define VPAD 3072

// fused-prep role ranges (blocks of 256 threads)
#define NB_CVTW   8192    // 2 * G4 * 512 / 256
#define NB_WOUT   12288   // VPAD * 1024 / 256
#define NB_XS     16384   // T * B * E / 256
#define NB_CARRY  512     // B * H / 256

typedef short bf16x8 __attribute__((ext_vector_type(8)));
typedef float f32x4 __attribute__((ext_vector_type(4)));

__device__ __forceinline__ unsigned short f2b(float f){
  union { float f; unsigned int u; } x; x.f = f;
  unsigned int u = x.u;
  unsigned int r = (u + 0x7fffu + ((u >> 16) & 1u)) >> 16;
  return (unsigned short)r;
}
__device__ __forceinline__ float b2f(unsigned short h){
  union { unsigned int u; float f; } x; x.u = ((unsigned int)h) << 16;
  return x.f;
}
__device__ __forceinline__ float sigm(float x){ return 1.0f / (1.0f + expf(-x)); }

__device__ __forceinline__ void gload_lds16(const unsigned short* g, unsigned short* l){
  __builtin_amdgcn_global_load_lds(
      (const __attribute__((address_space(1))) unsigned int*)g,
      (__attribute__((address_space(3))) unsigned int*)l, 16, 0, 0);
}

// ---------------- fused prep: all independent input->workspace transforms ----------------
__global__ __launch_bounds__(256) void k_prep(
    const float* __restrict__ wih, const float* __restrict__ whh,
    const float* __restrict__ wout,
    const float* __restrict__ img, const float* __restrict__ txt,
    const float* __restrict__ emb, const int* __restrict__ ans,
    const float* __restrict__ h0, const float* __restrict__ c0,
    const int* __restrict__ lengths,
    unsigned short* __restrict__ o_ih, unsigned short* __restrict__ o_hh,
    unsigned short* __restrict__ o_wo, unsigned short* __restrict__ xs,
    unsigned short* __restrict__ hx, float* __restrict__ cx,
    int* __restrict__ bs, int* __restrict__ roff, int* __restrict__ meta,
    int* __restrict__ rmap){
  int bid = blockIdx.x;
  if (bid < NB_CVTW){
    int i = bid * 256 + threadIdx.x;
    int n1 = G4 * EDIM;
    if (i < n1) o_ih[i] = f2b(wih[i]);
    else o_hh[i - n1] = f2b(whh[i - n1]);
    return;
  }
  bid -= NB_CVTW;
  if (bid < NB_WOUT){
    int i = bid * 256 + threadIdx.x;
    int r = i >> 10, c = i & 1023;
    o_wo[i] = (r < VOCAB) ? f2b(wout[r * 1024 + c]) : (unsigned short)0;
    return;
  }
  bid -= NB_WOUT;
  if (bid < NB_XS){
    int i = bid * 256 + threadIdx.x;
    int e = i & (EDIM - 1);
    int r = i >> 9;              // t*B + b
    int t = r >> 8, b = r & 255;
    float v;
    if (t == 0) v = (e < 256) ? img[b * 256 + e] : txt[b * 256 + (e - 256)];
    else { int tok = ans[b * T_STEPS + (t - 1)]; v = emb[(size_t)tok * EDIM + e]; }
    xs[i] = f2b(v);
    return;
  }
  bid -= NB_XS;
  if (bid < NB_CARRY){
    int i = bid * 256 + threadIdx.x;
    hx[i] = f2b(h0[i]); cx[i] = c0[i];
    return;
  }
  // ---- lens role: one block, 256 threads ----
  {
    __shared__ int s[T_STEPS];
    __shared__ int sroff[T_STEPS + 1];
    int t = threadIdx.x;
    if (t < T_STEPS){
      int c = 0;
      for (int i = 0; i < BATCH; i++) c += (lengths[i] > t) ? 1 : 0;
      s[t] = c; bs[t] = c;
    }
    __syncthreads();
    if (t == 0){
      int acc = 0;
      for (int u = 0; u < T_STEPS; u++){ sroff[u] = acc; roff[u] = acc; acc += s[u]; }
      sroff[T_STEPS] = acc;
      meta[0] = acc;
    }
    __syncthreads();
    int ntot = sroff[T_STEPS];
    for (int r = t; r < T_STEPS * BATCH; r += 256){
      int tt = r >> 8, b = r & 255;
      if (b < s[tt]) rmap[sroff[tt] + b] = r;
    }
    for (int r = ntot + t; r < T_STEPS * BATCH; r += 256) rmap[r] = -1;
  }
}

// ---------------- staged 128x128 GEMM core, BK=64, XOR-swizzled LDS ----------------
template<int K>
__device__ __forceinline__ void gemm_tile(const unsigned short* __restrict__ A,
                                          const unsigned short* __restrict__ B,
                                          int row0, int col0,
                                          unsigned short* As, unsigned short* Bs,
                                          f32x4 acc[4][4]){
  const int tid = threadIdx.x, w = tid >> 6, l = tid & 63;
  const int la = l & 15, lkq = l >> 4;
  const int sr = l >> 3;            // row within 8-row staging group
  const int ss = (l & 7) ^ sr;      // pre-swizzled source slot
  const int wr = (w >> 1) * 64, wc = (w & 1) * 64;
  const unsigned short* gA = A + (size_t)(row0 + w * 32 + sr) * K + ss * 8;
  const unsigned short* gB = B + (size_t)(col0 + w * 32 + sr) * K + ss * 8;
  unsigned short* lA = As + (w * 32) * 64;
  unsigned short* lB = Bs + (w * 32) * 64;
  for (int k0 = 0; k0 < K; k0 += 64){
#pragma unroll
    for (int i = 0; i < 4; i++){
      gload_lds16(gA + (size_t)i * 8 * K + k0, lA + i * 8 * 64);
      gload_lds16(gB + (size_t)i * 8 * K + k0, lB + i * 8 * 64);
    }
    __syncthreads();
#pragma unroll
    for (int kk = 0; kk < 2; kk++){
      bf16x8 a[4], b[4];
#pragma unroll
      for (int i = 0; i < 4; i++){
        int r = wr + i * 16 + la;
        a[i] = *(const bf16x8*)(As + r * 64 + (((kk * 4 + lkq) ^ (r & 7)) << 3));
      }
#pragma unroll
      for (int i = 0; i < 4; i++){
        int r = wc + i * 16 + la;
        b[i] = *(const bf16x8*)(Bs + r * 64 + (((kk * 4 + lkq) ^ (r & 7)) << 3));
      }
#pragma unroll
      for (int mi = 0; mi < 4; mi++)
#pragma unroll
        for (int ni = 0; ni < 4; ni++)
          acc[mi][ni] = __builtin_amdgcn_mfma_f32_16x16x32_bf16(a[mi], b[ni], acc[mi][ni], 0, 0, 0);
    }
    __syncthreads();
  }
}

// ---------------- GEMM 1: XW = xs @ W_ih^T + b_ih + b_hh (bf16 out) ----------------
__global__ __launch_bounds__(256) void k_gemm_xw(const unsigned short* __restrict__ A,
                                                 const unsigned short* __restrict__ W,
                                                 const float* __restrict__ bih,
                                                 const float* __restrict__ bhh,
                                                 unsigned short* __restrict__ C){
  __shared__ unsigned short As[128 * 64], Bs[128 * 64];
  int row0 = blockIdx.x * 128, col0 = blockIdx.y * 128;
  f32x4 acc[4][4] = {};
  gemm_tile<EDIM>(A, W, row0, col0, As, Bs, acc);
  int tid = threadIdx.x, w = tid >> 6, l = tid & 63;
  int la = l & 15, r4 = (l >> 4) * 4;
  int wr = (w >> 1) * 64, wc = (w & 1) * 64;
#pragma unroll
  for (int ni = 0; ni < 4; ni++){
    int col = col0 + wc + ni * 16 + la;
    float bias = bih[col] + bhh[col];
#pragma unroll
    for (int mi = 0; mi < 4; mi++)
#pragma unroll
      for (int j = 0; j < 4; j++){
        int row = row0 + wr + mi * 16 + r4 + j;
        C[(size_t)row * G4 + col] = f2b(acc[mi][ni][j] + bias);
      }
  }
}

// ---------------- fused recurrent step: 512 blocks (16 rows x 16 hcols), wave=gate ----
// All 16 Whh B-fragments hoisted into registers -> one batched latency exposure.
__global__ __launch_bounds__(256, 2) void k_lstm_step(
    const unsigned short* __restrict__ XWt,
    const unsigned short* __restrict__ Whh,
    const unsigned short* __restrict__ hin,
    unsigned short* __restrict__ hout,
    float* __restrict__ cxio,
    unsigned short* __restrict__ hs_t,
    unsigned short* __restrict__ cs_t,
    const unsigned short* __restrict__ hs_m2,
    const unsigned short* __restrict__ cs_m2,
    int do_res){
  __shared__ unsigned short hA[16 * 512];   // swizzled h tile
  __shared__ float gbuf[4][16][17];
  const int w = threadIdx.x >> 6, l = threadIdx.x & 63;
  const int la = l & 15, lkq = l >> 4;
  const int row0 = blockIdx.x * 16;
  const int hc0  = blockIdx.y * 16;
  // stage h tile: wave w stages rows {w, 4+w, 8+w, 12+w}; source slot pre-swizzled
#pragma unroll
  for (int i = 0; i < 4; i++){
    int r = i * 4 + w;
    gload_lds16(hin + (size_t)(row0 + r) * HDIM + ((l ^ (r & 7)) << 3), hA + r * 512);
  }
  // hoist ALL 16 Whh B-fragments (independent, issued back-to-back)
  const unsigned short* Bp = Whh + (size_t)(w * HDIM + hc0 + la) * HDIM + lkq * 8;
  bf16x8 b[16];
#pragma unroll
  for (int kk = 0; kk < 16; kk++) b[kk] = *(const bf16x8*)(Bp + kk * 32);
  // hoist XW (consumed after MFMA loop)
  const int r4 = lkq * 4;
  float x[4];
#pragma unroll
  for (int j = 0; j < 4; j++)
    x[j] = b2f(XWt[(size_t)(row0 + r4 + j) * G4 + w * HDIM + hc0 + la]);
  __syncthreads();
  f32x4 acc = {};
#pragma unroll
  for (int kk = 0; kk < 16; kk++){
    bf16x8 a = *(const bf16x8*)(hA + la * 512 + (((kk * 4 + lkq) ^ (la & 7)) << 3));
    acc = __builtin_amdgcn_mfma_f32_16x16x32_bf16(a, b[kk], acc, 0, 0, 0);
  }
#pragma unroll
  for (int j = 0; j < 4; j++) gbuf[w][r4 + j][la] = acc[j] + x[j];
  __syncthreads();
  {
    int r = threadIdx.x >> 4, c = threadIdx.x & 15;
    size_t p = (size_t)(row0 + r) * HDIM + hc0 + c;
    float gi = gbuf[0][r][c], gf = gbuf[1][r][c], gg = gbuf[2][r][c], go = gbuf[3][r][c];
    float cprev = cxio[p];
    float cy = sigm(gf) * cprev + sigm(gi) * tanhf(gg);
    float hy = sigm(go) * tanhf(cy);
    hs_t[p] = f2b(hy);
    cs_t[p] = f2b(cy);
    float hn = hy, cn = cy;
    if (do_res){ hn += b2f(hs_m2[p]); cn += b2f(cs_m2[p]); }
    hout[p] = f2b(hn);
    cxio[p] = cn;
  }
}

// ---------------- GEMM 2: packed output projection, A gathered via rmap ----------------
__global__ __launch_bounds__(256) void k_gemm_out(const unsigned short* __restrict__ hs,
                                                  const unsigned short* __restrict__ cs,
                                                  const unsigned short* __restrict__ Wo,
                                                  const float* __restrict__ bout,
                                                  const int* __restrict__ meta,
                                                  const int* __restrict__ rmap,
                                                  float* __restrict__ out){
  int ntot = meta[0];
  int row0 = blockIdx.x * 128, col0 = blockIdx.y * 128;
  if (row0 >= ntot) return;
  __shared__ unsigned short As[128 * 64], Bs[128 * 64];
  const int tid = threadIdx.x, w = tid >> 6, l = tid & 63;
  const int la = l & 15, lkq = l >> 4;
  const int sr = l >> 3, ss = (l & 7) ^ sr;
  const int wr = (w >> 1) * 64, wc = (w & 1) * 64;
  int srow[4];
#pragma unroll
  for (int i = 0; i < 4; i++){
    int rr = rmap[row0 + w * 32 + sr + i * 8];
    srow[i] = rr < 0 ? 0 : rr;
  }
  const unsigned short* gB = Wo + (size_t)(col0 + w * 32 + sr) * 1024 + ss * 8;
  unsigned short* lA = As + (w * 32) * 64;
  unsigned short* lB = Bs + (w * 32) * 64;
  f32x4 acc[4][4] = {};
  for (int k0 = 0; k0 < 1024; k0 += 64){
#pragma unroll
    for (int i = 0; i < 4; i++){
      const unsigned short* srcA = (k0 < 512)
          ? hs + (size_t)srow[i] * 512 + k0 + ss * 8
          : cs + (size_t)srow[i] * 512 + (k0 - 512) + ss * 8;
      gload_lds16(srcA, lA + i * 8 * 64);
      gload_lds16(gB + (size_t)i * 8 * 1024 + k0, lB + i * 8 * 64);
    }
    __syncthreads();
#pragma unroll
    for (int kk = 0; kk < 2; kk++){
      bf16x8 a[4], b[4];
#pragma unroll
      for (int i = 0; i < 4; i++){
        int r = wr + i * 16 + la;
        a[i] = *(const bf16x8*)(As + r * 64 + (((kk * 4 + lkq) ^ (r & 7)) << 3));
      }
#pragma unroll
      for (int i = 0; i < 4; i++){
        int r = wc + i * 16 + la;
        b[i] = *(const bf16x8*)(Bs + r * 64 + (((kk * 4 + lkq) ^ (r & 7)) << 3));
      }
#pragma unroll
      for (int mi = 0; mi < 4; mi++)
#pragma unroll
        for (int ni = 0; ni < 4; ni++)
          acc[mi][ni] = __builtin_amdgcn_mfma_f32_16x16x32_bf16(a[mi], b[ni], acc[mi][ni], 0, 0, 0);
    }
    __syncthreads();
  }
  int r4 = (l >> 4) * 4;
#pragma unroll
  for (int ni = 0; ni < 4; ni++){
    int col = col0 + wc + ni * 16 + la;
    if (col >= VOCAB) continue;
    float bias = bout[col];
#pragma unroll
    for (int mi = 0; mi < 4; mi++)
#pragma unroll
      for (int j = 0; j < 4; j++){
        int row = row0 + wr + mi * 16 + r4 + j;
        if (row < ntot) out[(size_t)row * VOCAB + col] = acc[mi][ni][j] + bias;
      }
  }
}

extern "C" void kernel_launch(void* const* d_in, const int* in_sizes, int n_in,
                              void* d_out, int out_size, void* d_ws, size_t ws_size,
                              hipStream_t stream){
  const float* img   = (const float*)d_in[0];
  const float* txt   = (const float*)d_in[1];
  const float* h0    = (const float*)d_in[2];
  const float* c0    = (const float*)d_in[3];
  const float* emb   = (const float*)d_in[4];
  const float* W_ih  = (const float*)d_in[5];
  const float* W_hh  = (const float*)d_in[6];
  const float* b_ih  = (const float*)d_in[7];
  const float* b_hh  = (const float*)d_in[8];
  const float* W_out = (const float*)d_in[9];
  const float* b_out = (const float*)d_in[10];
  const int* answer  = (const int*)d_in[11];
  const int* lengths = (const int*)d_in[12];
  float* out = (float*)d_out;

  char* ws = (char*)d_ws;
  size_t off = 0;
  auto alloc = [&](size_t bytes) -> void* {
    void* p = ws + off; off += (bytes + 255) & ~(size_t)255; return p;
  };
  unsigned short* Wih_b = (unsigned short*)alloc((size_t)G4 * EDIM * 2);
  unsigned short* Whh_b = (unsigned short*)alloc((size_t)G4 * HDIM * 2);
  unsigned short* Wo_b  = (unsigned short*)alloc((size_t)VPAD * 1024 * 2);
  unsigned short* xs    = (unsigned short*)alloc((size_t)T_STEPS * BATCH * EDIM * 2);
  unsigned short* XW    = (unsigned short*)alloc((size_t)T_STEPS * BATCH * G4 * 2);
  unsigned short* hs    = (unsigned short*)alloc((size_t)T_STEPS * BATCH * HDIM * 2);
  unsigned short* cs    = (unsigned short*)alloc((size_t)T_STEPS * BATCH * HDIM * 2);
  unsigned short* hxA   = (unsigned short*)alloc((size_t)BATCH * HDIM * 2);
  unsigned short* hxB   = (unsigned short*)alloc((size_t)BATCH * HDIM * 2);
  float* cx             = (float*)alloc((size_t)BATCH * HDIM * 4);
  int* bsz  = (int*)alloc(T_STEPS * 4);
  int* roff = (int*)alloc(T_STEPS * 4);
  int* meta = (int*)alloc(256);
  int* rmap = (int*)alloc(T_STEPS * BATCH * 4);

  k_prep<<<dim3(NB_CVTW + NB_WOUT + NB_XS + NB_CARRY + 1), 256, 0, stream>>>(
      W_ih, W_hh, W_out, img, txt, emb, answer, h0, c0, lengths,
      Wih_b, Whh_b, Wo_b, xs, hxA, cx, bsz, roff, meta, rmap);

  k_gemm_xw<<<dim3(T_STEPS * BATCH / 128, G4 / 128), 256, 0, stream>>>(xs, Wih_b, b_ih, b_hh, XW);

  unsigned short* hbuf[2] = { hxA, hxB };
  for (int t = 0; t < T_STEPS; t++){
    int do_res = (t >= 2 && (t % 3) == 0) ? 1 : 0;
    int tm2 = (t >= 2) ? (t - 2) : 0;
    k_lstm_step<<<dim3(BATCH / 16, HDIM / 16), 256, 0, stream>>>(
        XW + (size_t)t * BATCH * G4, Whh_b, hbuf[t & 1], hbuf[(t + 1) & 1], cx,
        hs + (size_t)t * BATCH * HDIM, cs + (size_t)t * BATCH * HDIM,
        hs + (size_t)tm2 * BATCH * HDIM, cs + (size_t)tm2 * BATCH * HDIM, do_res);
  }

  k_gemm_out<<<dim3(T_STEPS * BATCH / 128, VPAD / 128), 256, 0, stream>>>(hs, cs, Wo_b, b_out, meta, rmap, out);
}